// Round 4
// baseline (3117.835 us; speedup 1.0000x reference)
//
#include <hip/hip_runtime.h>
#include <math.h>

#define NN 1048576
#define EE 4194304
#define NBUCK 256
#define BNODES 4096          // nodes per bucket (NN / NBUCK)
#define CAP 20480            // bucket edge capacity (mean 16384, sigma~128)
#define NPB 256              // nodes per block in conv layers (divides BNODES)
#define LPAD 13              // LDS accumulator stride (floats) -> conflict-free
constexpr float BN_EPS = 1e-5f;

typedef _Float16 half8  __attribute__((ext_vector_type(8)));

// ---- workspace layout (bytes), total 96 MB ----
#define OFF_SSRC    0u                        // NBUCK*CAP ints = 20 MB (packed src|dloc)
#define OFF_ROWPTR  20971520u                 // N ints = 4 MB
#define OFF_ROWEND  25165824u                 // N ints = 4 MB
#define OFF_CURSOR  29360128u                 // NBUCK ints
#define OFF_STATS   (29360128u + 4096u)       // 10*SS floats
#define OFF_HA      33554432u                 // N*16 halves = 32 MB
#define OFF_HB      67108864u                 // N*16 halves = 32 MB
#define OFF_EBUF    33554432u                 // NBUCK*CAP int2 = 40 MB (aliases hA/hB; dead before conv1)
#define SS 384                                // stats slot stride (floats): 24 counters * 16

// ================= init: bucket cursors + stats zero =================
__global__ void k_init(int* __restrict__ cursor, float* __restrict__ stats){
  int t = threadIdx.x;
  cursor[t] = t * CAP;
  for(int i = t; i < 10*SS; i += 256) stats[i] = 0.0f;
}

// ============ pass B: bin edges into 256 buckets by dst>>12 ============
__global__ void k_bucket(const int* __restrict__ src, const int* __restrict__ dst,
                         int* __restrict__ cursor, int2* __restrict__ ebuf){
  __shared__ int hist[NBUCK];
  __shared__ int base[NBUCK];
  int t = threadIdx.x;
  hist[t] = 0;
  __syncthreads();
  int eb = blockIdx.x * 4096;
  int s[16], d[16], r[16];
#pragma unroll
  for(int k=0; k<16; k++){
    int e = eb + k*256 + t;
    s[k] = src[e];
    d[k] = dst[e];
    r[k] = atomicAdd(&hist[d[k] >> 12], 1);
  }
  __syncthreads();
  base[t] = atomicAdd(&cursor[t], hist[t]);
  __syncthreads();
#pragma unroll
  for(int k=0; k<16; k++){
    int b = d[k] >> 12;
    int pos = base[b] + r[k];
    if(pos < (b+1)*CAP)                 // capacity guard (never triggers for this data)
      ebuf[pos] = make_int2(s[k], d[k]);
  }
}

// ===== pass C: per-bucket counting sort -> rowptr/rowend/ssrc (packed) =====
__global__ void k_csr(const int2* __restrict__ ebuf, const int* __restrict__ cursor,
                      int* __restrict__ ssrc, int* __restrict__ rowptr,
                      int* __restrict__ rowend){
  __shared__ int hist[BNODES];
  __shared__ int part[256];
  int b = blockIdx.x, t = threadIdx.x;
  int cnt = cursor[b] - b*CAP;
  if(cnt > CAP) cnt = CAP;
  int ebase = b*CAP;
  for(int i=t; i<BNODES; i+=256) hist[i] = 0;
  __syncthreads();
  for(int i=t; i<cnt; i+=256){
    int2 e = ebuf[ebase + i];
    atomicAdd(&hist[e.y & (BNODES-1)], 1);
  }
  __syncthreads();
  int loc[16]; int sum = 0;
#pragma unroll
  for(int j=0; j<16; j++){ loc[j] = hist[t*16 + j]; sum += loc[j]; }
  part[t] = sum;
  __syncthreads();
#pragma unroll
  for(int off=1; off<256; off<<=1){
    int v = (t >= off) ? part[t-off] : 0;
    __syncthreads();
    part[t] += v;
    __syncthreads();
  }
  int run = part[t] - sum;   // exclusive prefix for this thread's 16 nodes
#pragma unroll
  for(int j=0; j<16; j++){
    int n = b*BNODES + t*16 + j;
    rowptr[n] = ebase + run;
    rowend[n] = ebase + run + loc[j];
    hist[t*16 + j] = run;
    run += loc[j];
  }
  __syncthreads();
  for(int i=t; i<cnt; i+=256){
    int2 e = ebuf[ebase + i];
    int pos = atomicAdd(&hist[e.y & (BNODES-1)], 1);
    // pack: src (20 bits, N=2^20) | dst-local-within-256 (8 bits) << 20
    ssrc[ebase + pos] = e.x | ((e.y & (NPB-1)) << 20);
  }
}

// ================= stats helpers =================
template<int NF>
__device__ __forceinline__ void stats_flush(float* ssum, float* ssq,
                                            float* __restrict__ stats_out){
  __shared__ float sred[2*NF];
#pragma unroll
  for(int f=0; f<NF; f++){
    float a = ssum[f], b = ssq[f];
#pragma unroll
    for(int off=1; off<64; off<<=1){
      a += __shfl_xor(a, off, 64);
      b += __shfl_xor(b, off, 64);
    }
    ssum[f] = a; ssq[f] = b;
  }
  if(threadIdx.x < 2*NF) sred[threadIdx.x] = 0.0f;
  __syncthreads();
  if((threadIdx.x & 63) == 0){
#pragma unroll
    for(int f=0; f<NF; f++){
      atomicAdd(&sred[f],      ssum[f]);
      atomicAdd(&sred[NF + f], ssq[f]);
    }
  }
  __syncthreads();
  if(threadIdx.x < 2*NF)
    atomicAdd(&stats_out[threadIdx.x * 16], sred[threadIdx.x]);  // 64B-spread counters
}

__device__ __forceinline__ void store_row16(_Float16* __restrict__ hout, int i,
                                            const float* ov){
  half8 o0, o1;
#pragma unroll
  for(int j=0; j<8; j++) o0[j] = (_Float16)ov[j];
#pragma unroll
  for(int j=0; j<4; j++) o1[j] = (_Float16)ov[8+j];
  o1[4]=(_Float16)0.f; o1[5]=(_Float16)0.f; o1[6]=(_Float16)0.f; o1[7]=(_Float16)0.f;
  half8* op = (half8*)(hout + 16*i);
  op[0] = o0; op[1] = o1;
}

// ===== conv layer 1 (edge-parallel): x[N,3] fp32 -> h[N,16] fp16 =====
__global__ __launch_bounds__(256) void
k_layer1(const float* __restrict__ x,
         const int* __restrict__ rowptr, const int* __restrict__ rowend,
         const int* __restrict__ ssrc,
         const float* __restrict__ Wl1, const float* __restrict__ Wr1,
         const float* __restrict__ b1,
         _Float16* __restrict__ hout, float* __restrict__ stats_out){
  __shared__ float acc[NPB*5];
  int t = threadIdx.x;
  int nbase = blockIdx.x * NPB;
#pragma unroll
  for(int i=t; i<NPB*5; i+=256) acc[i] = 0.0f;
  __syncthreads();
  int estart = rowptr[nbase];
  int eend   = rowend[nbase + NPB - 1];
  int e = estart + t;
  for(; e + 768 < eend; e += 1024){
    unsigned v0=ssrc[e], v1=ssrc[e+256], v2=ssrc[e+512], v3=ssrc[e+768];
    const float* p0 = x + 3*(v0 & 0xFFFFF);
    const float* p1 = x + 3*(v1 & 0xFFFFF);
    const float* p2 = x + 3*(v2 & 0xFFFFF);
    const float* p3 = x + 3*(v3 & 0xFFFFF);
    float a0=p0[0], a1=p0[1], a2=p0[2];
    float b0=p1[0], b1_=p1[1], b2=p1[2];
    float c0=p2[0], c1=p2[1], c2=p2[2];
    float d0=p3[0], d1=p3[1], d2=p3[2];
    float* q0 = &acc[(v0 >> 20)*5];
    float* q1 = &acc[(v1 >> 20)*5];
    float* q2 = &acc[(v2 >> 20)*5];
    float* q3 = &acc[(v3 >> 20)*5];
    atomicAdd(&q0[0],a0); atomicAdd(&q0[1],a1); atomicAdd(&q0[2],a2);
    atomicAdd(&q1[0],b0); atomicAdd(&q1[1],b1_); atomicAdd(&q1[2],b2);
    atomicAdd(&q2[0],c0); atomicAdd(&q2[1],c1); atomicAdd(&q2[2],c2);
    atomicAdd(&q3[0],d0); atomicAdd(&q3[1],d1); atomicAdd(&q3[2],d2);
  }
  for(; e < eend; e += 256){
    unsigned v = ssrc[e];
    const float* p = x + 3*(v & 0xFFFFF);
    float a0=p[0], a1=p[1], a2=p[2];
    float* q = &acc[(v >> 20)*5];
    atomicAdd(&q[0],a0); atomicAdd(&q[1],a1); atomicAdd(&q[2],a2);
  }
  __syncthreads();
  // phase B: one node per thread
  int i = nbase + t;
  int st = rowptr[i], en = rowend[i];
  float inv = (en > st) ? 1.0f/(float)(en-st) : 0.0f;
  float a0 = acc[t*5+0]*inv, a1 = acc[t*5+1]*inv, a2 = acc[t*5+2]*inv;
  float x0 = x[3*i], x1 = x[3*i+1], x2 = x[3*i+2];
  float ssum[12], ssq[12], ov[12];
#pragma unroll
  for(int f=0; f<12; f++){
    float o = b1[f]
            + Wl1[3*f]*a0 + Wl1[3*f+1]*a1 + Wl1[3*f+2]*a2
            + Wr1[3*f]*x0 + Wr1[3*f+1]*x1 + Wr1[3*f+2]*x2;
    o = fmaxf(o, 0.0f);
    ov[f] = o; ssum[f] = o; ssq[f] = o*o;
  }
  store_row16(hout, i, ov);
  stats_flush<12>(ssum, ssq, stats_out);
}

// ===== conv layers 2..8 (edge-parallel): BN folded + SAGE, fp16 -> fp16 =====
template<bool STATS>
__global__ __launch_bounds__(256) void
k_layerk(const _Float16* __restrict__ hin,
         const int* __restrict__ rowptr, const int* __restrict__ rowend,
         const int* __restrict__ ssrc,
         const float* __restrict__ Wl, const float* __restrict__ Wr,
         const float* __restrict__ bias,
         const float* __restrict__ bng, const float* __restrict__ bnb,
         const float* __restrict__ stats_in,
         _Float16* __restrict__ hout, float* __restrict__ stats_out){
  __shared__ float acc[NPB*LPAD];
  int t = threadIdx.x;
  int nbase = blockIdx.x * NPB;
#pragma unroll
  for(int i=t; i<NPB*LPAD; i+=256) acc[i] = 0.0f;
  __syncthreads();
  int estart = rowptr[nbase];
  int eend   = rowend[nbase + NPB - 1];
  int e = estart + t;
  for(; e + 768 < eend; e += 1024){
    unsigned v0=ssrc[e], v1=ssrc[e+256], v2=ssrc[e+512], v3=ssrc[e+768];
    const half8* p0 = (const half8*)(hin + 16*(v0 & 0xFFFFF));
    const half8* p1 = (const half8*)(hin + 16*(v1 & 0xFFFFF));
    const half8* p2 = (const half8*)(hin + 16*(v2 & 0xFFFFF));
    const half8* p3 = (const half8*)(hin + 16*(v3 & 0xFFFFF));
    half8 a0=p0[0], a1=p0[1];
    half8 b0=p1[0], b1=p1[1];
    half8 c0=p2[0], c1=p2[1];
    half8 d0=p3[0], d1=p3[1];
    float* q0 = &acc[(v0 >> 20)*LPAD];
    float* q1 = &acc[(v1 >> 20)*LPAD];
    float* q2 = &acc[(v2 >> 20)*LPAD];
    float* q3 = &acc[(v3 >> 20)*LPAD];
#pragma unroll
    for(int k=0; k<8; k++) atomicAdd(&q0[k], (float)a0[k]);
#pragma unroll
    for(int k=0; k<4; k++) atomicAdd(&q0[8+k], (float)a1[k]);
#pragma unroll
    for(int k=0; k<8; k++) atomicAdd(&q1[k], (float)b0[k]);
#pragma unroll
    for(int k=0; k<4; k++) atomicAdd(&q1[8+k], (float)b1[k]);
#pragma unroll
    for(int k=0; k<8; k++) atomicAdd(&q2[k], (float)c0[k]);
#pragma unroll
    for(int k=0; k<4; k++) atomicAdd(&q2[8+k], (float)c1[k]);
#pragma unroll
    for(int k=0; k<8; k++) atomicAdd(&q3[k], (float)d0[k]);
#pragma unroll
    for(int k=0; k<4; k++) atomicAdd(&q3[8+k], (float)d1[k]);
  }
  for(; e < eend; e += 256){
    unsigned v = ssrc[e];
    const half8* p = (const half8*)(hin + 16*(v & 0xFFFFF));
    half8 a0=p[0], a1=p[1];
    float* q = &acc[(v >> 20)*LPAD];
#pragma unroll
    for(int k=0; k<8; k++) atomicAdd(&q[k], (float)a0[k]);
#pragma unroll
    for(int k=0; k<4; k++) atomicAdd(&q[8+k], (float)a1[k]);
  }
  __syncthreads();
  // phase B: one node per thread
  float sc[12], sh[12];
#pragma unroll
  for(int f=0; f<12; f++){
    float m = stats_in[f*16]      * (1.0f/NN);
    float v = stats_in[(12+f)*16] * (1.0f/NN) - m*m;
    float is = rsqrtf(v + BN_EPS);
    sc[f] = bng[f]*is;
    sh[f] = bnb[f] - m*sc[f];
  }
  int i = nbase + t;
  int st = rowptr[i], en = rowend[i];
  float inv   = (en > st) ? 1.0f/(float)(en-st) : 0.0f;
  float zmask = (en > st) ? 1.0f : 0.0f;
  const half8* hp = (const half8*)(hin + 16*i);
  half8 r0 = hp[0], r1 = hp[1];
  float hi[12];
#pragma unroll
  for(int k=0; k<8; k++) hi[k] = (float)r0[k];
#pragma unroll
  for(int k=0; k<4; k++) hi[8+k] = (float)r1[k];
  float aggn[12], hn[12];
#pragma unroll
  for(int k=0; k<12; k++){
    aggn[k] = (acc[t*LPAD+k]*inv*sc[k] + sh[k]) * zmask;  // BN-of-mean; deg=0 -> 0
    hn[k]   = hi[k]*sc[k] + sh[k];
  }
  float ssum[12], ssq[12], ov[12];
#pragma unroll
  for(int f=0; f<12; f++){
    float o = bias[f];
#pragma unroll
    for(int k=0; k<12; k++) o += Wl[12*f+k]*aggn[k];
#pragma unroll
    for(int k=0; k<12; k++) o += Wr[12*f+k]*hn[k];
    o = fmaxf(o, 0.0f);
    ov[f] = o;
    ssum[f] = o; ssq[f] = o*o;
  }
  store_row16(hout, i, ov);
  if(STATS) stats_flush<12>(ssum, ssq, stats_out);
}

// ========== head linear on [2N,6] stored as padded fp16 [N,16] ==========
// one thread = one padded row = two consecutive [2N,6] sub-rows
template<bool FIRST>
__global__ void k_head(const _Float16* __restrict__ zin,
                       const float* __restrict__ W, const float* __restrict__ bv,
                       const float* __restrict__ g6, const float* __restrict__ b6,
                       const float* __restrict__ stats_in,
                       _Float16* __restrict__ zout, float* __restrict__ stats_out){
  float sc[6], sh[6];
  if(!FIRST){
#pragma unroll
    for(int k=0; k<6; k++){
      float m = stats_in[k*16]     * (1.0f/(2.0f*NN));
      float v = stats_in[(6+k)*16] * (1.0f/(2.0f*NN)) - m*m;
      float is = rsqrtf(v + BN_EPS);
      sc[k] = g6[k]*is;
      sh[k] = b6[k] - m*sc[k];
    }
  }
  float ssum[6], ssq[6];
#pragma unroll
  for(int f=0; f<6; f++){ ssum[f]=0.f; ssq[f]=0.f; }
  int stride = gridDim.x*blockDim.x;
  for(int i = blockIdx.x*blockDim.x + threadIdx.x; i < NN; i += stride){
    const half8* zp = (const half8*)(zin + 16*i);
    half8 a = zp[0], b = zp[1];
    float t0[6] = {(float)a[0],(float)a[1],(float)a[2],(float)a[3],(float)a[4],(float)a[5]};
    float t1[6] = {(float)a[6],(float)a[7],(float)b[0],(float)b[1],(float)b[2],(float)b[3]};
    if(!FIRST){
#pragma unroll
      for(int k=0; k<6; k++){
        t0[k] = fmaxf(t0[k]*sc[k] + sh[k], 0.0f);
        t1[k] = fmaxf(t1[k]*sc[k] + sh[k], 0.0f);
      }
    }
    float ov[12];
#pragma unroll
    for(int f=0; f<6; f++){
      float o0 = bv[f], o1 = bv[f];
#pragma unroll
      for(int k=0; k<6; k++){ o0 += W[6*f+k]*t0[k]; o1 += W[6*f+k]*t1[k]; }
      ov[f] = o0; ov[6+f] = o1;
      ssum[f] += o0 + o1; ssq[f] += o0*o0 + o1*o1;
    }
    store_row16(zout, i, ov);
  }
  stats_flush<6>(ssum, ssq, stats_out);
}

// ========== final: BN+ReLU + Linear(6,1) + sigmoid; one thread = 2 outputs ==========
__global__ void k_out(const _Float16* __restrict__ zin,
                      const float* __restrict__ g6, const float* __restrict__ b6,
                      const float* __restrict__ stats_in,
                      const float* __restrict__ outW, const float* __restrict__ outb,
                      float* __restrict__ out){
  float sc[6], sh[6], w[6];
#pragma unroll
  for(int k=0; k<6; k++){
    float m = stats_in[k*16]     * (1.0f/(2.0f*NN));
    float v = stats_in[(6+k)*16] * (1.0f/(2.0f*NN)) - m*m;
    float is = rsqrtf(v + BN_EPS);
    sc[k] = g6[k]*is;
    sh[k] = b6[k] - m*sc[k];
    w[k] = outW[k];
  }
  float ob = outb[0];
  int stride = gridDim.x*blockDim.x;
  for(int i = blockIdx.x*blockDim.x + threadIdx.x; i < NN; i += stride){
    const half8* zp = (const half8*)(zin + 16*i);
    half8 a = zp[0], b = zp[1];
    float t0[6] = {(float)a[0],(float)a[1],(float)a[2],(float)a[3],(float)a[4],(float)a[5]};
    float t1[6] = {(float)a[6],(float)a[7],(float)b[0],(float)b[1],(float)b[2],(float)b[3]};
    float o0 = ob, o1 = ob;
#pragma unroll
    for(int k=0; k<6; k++){
      o0 += w[k] * fmaxf(t0[k]*sc[k] + sh[k], 0.0f);
      o1 += w[k] * fmaxf(t1[k]*sc[k] + sh[k], 0.0f);
    }
    float2 r;
    r.x = 1.0f / (1.0f + expf(-o0));
    r.y = 1.0f / (1.0f + expf(-o1));
    ((float2*)out)[i] = r;
  }
}

extern "C" void kernel_launch(void* const* d_in, const int* in_sizes, int n_in,
                              void* d_out, int out_size, void* d_ws, size_t ws_size,
                              hipStream_t stream){
  const float* x    = (const float*)d_in[0];
  const int*   ei   = (const int*)  d_in[1];
  const float* Wl1  = (const float*)d_in[2];
  const float* Wr1  = (const float*)d_in[3];
  const float* b1   = (const float*)d_in[4];
  const float* Wl   = (const float*)d_in[5];
  const float* Wr   = (const float*)d_in[6];
  const float* bb   = (const float*)d_in[7];
  const float* bng  = (const float*)d_in[8];
  const float* bnb  = (const float*)d_in[9];
  const float* linW = (const float*)d_in[10];
  const float* linb = (const float*)d_in[11];
  const float* bn6g = (const float*)d_in[12];
  const float* bn6b = (const float*)d_in[13];
  const float* outW = (const float*)d_in[14];
  const float* outb = (const float*)d_in[15];
  float* out = (float*)d_out;

  char* ws = (char*)d_ws;
  int*      ssrc   = (int*)     (ws + OFF_SSRC);
  int*      rowptr = (int*)     (ws + OFF_ROWPTR);
  int*      rowend = (int*)     (ws + OFF_ROWEND);
  int*      cursor = (int*)     (ws + OFF_CURSOR);
  float*    stats  = (float*)   (ws + OFF_STATS);
  _Float16* hA     = (_Float16*)(ws + OFF_HA);
  _Float16* hB     = (_Float16*)(ws + OFF_HB);
  int2*     ebuf   = (int2*)    (ws + OFF_EBUF);   // aliases hA/hB; dead after k_csr

  const int* srcp = ei;
  const int* dstp = ei + EE;

  k_init  <<<1,    256, 0, stream>>>(cursor, stats);
  k_bucket<<<1024, 256, 0, stream>>>(srcp, dstp, cursor, ebuf);
  k_csr   <<<NBUCK,256, 0, stream>>>(ebuf, cursor, ssrc, rowptr, rowend);

  // conv1 (stats -> slot 0)
  k_layer1<<<NN/NPB, 256, 0, stream>>>(x, rowptr, rowend, ssrc, Wl1, Wr1, b1, hA, stats);

  // conv2..conv8
  _Float16* hi = hA; _Float16* ho = hB;
  for(int l=0; l<7; l++){
    const float* st_in = stats + l*SS;
    float* st_out      = stats + (l+1)*SS;
    if(l < 6)
      k_layerk<true><<<NN/NPB, 256, 0, stream>>>(hi, rowptr, rowend, ssrc,
        Wl + 144*l, Wr + 144*l, bb + 12*l, bng + 12*l, bnb + 12*l, st_in, ho, st_out);
    else
      k_layerk<false><<<NN/NPB, 256, 0, stream>>>(hi, rowptr, rowend, ssrc,
        Wl + 144*l, Wr + 144*l, bb + 12*l, bng + 12*l, bnb + 12*l, st_in, ho, st_out);
    _Float16* t = hi; hi = ho; ho = t;
  }
  // hi = conv8 output, padded fp16 rows; head views each row as two [2N,6] sub-rows

  // head: z1 (stats slot 7)
  k_head<true> <<<2048, 256, 0, stream>>>(hi, linW, linb, bn6g, bn6b,
                                          stats + 7*SS, ho, stats + 7*SS);
  { _Float16* t = hi; hi = ho; ho = t; }
  // z2 (slot 8)
  k_head<false><<<2048, 256, 0, stream>>>(hi, linW, linb, bn6g, bn6b,
                                          stats + 7*SS, ho, stats + 8*SS);
  { _Float16* t = hi; hi = ho; ho = t; }
  // z3 (slot 9)
  k_head<false><<<2048, 256, 0, stream>>>(hi, linW, linb, bn6g, bn6b,
                                          stats + 8*SS, ho, stats + 9*SS);
  { _Float16* t = hi; hi = ho; ho = t; }
  // final
  k_out<<<2048, 256, 0, stream>>>(hi, bn6g, bn6b, stats + 9*SS, outW, outb, out);
}

// Round 5
// 1394.783 us; speedup vs baseline: 2.2354x; 2.2354x over previous
//
#include <hip/hip_runtime.h>
#include <math.h>

#define NN 1048576
#define EE 4194304
#define NBUCK 256
#define BNODES 4096          // nodes per bucket (NN / NBUCK)
#define CAP 20480            // bucket edge capacity (mean 16384, sigma~128)
#define GBLK 2048            // conv grid: 2048*256 threads = NN/2 (2 nodes/thread)
constexpr float BN_EPS = 1e-5f;

typedef _Float16 half8  __attribute__((ext_vector_type(8)));

// ---- workspace layout (bytes), total 96 MB ----
#define OFF_SSRC    0u                        // NBUCK*CAP ints = 20 MB
#define OFF_ROWPTR  20971520u                 // N ints = 4 MB
#define OFF_ROWEND  25165824u                 // N ints = 4 MB
#define OFF_CURSOR  29360128u                 // NBUCK ints
#define OFF_STATS   (29360128u + 4096u)       // 10*SS floats
#define OFF_HA      33554432u                 // N*16 halves = 32 MB
#define OFF_HB      67108864u                 // N*16 halves = 32 MB
#define OFF_EBUF    33554432u                 // NBUCK*CAP int2 = 40 MB (aliases hA/hB; dead before conv1)
#define SS 384                                // stats slot stride (floats): 24 counters * 16

// ================= init: bucket cursors + stats zero =================
__global__ void k_init(int* __restrict__ cursor, float* __restrict__ stats){
  int t = threadIdx.x;
  cursor[t] = t * CAP;
  for(int i = t; i < 10*SS; i += 256) stats[i] = 0.0f;
}

// ============ pass B: bin edges into 256 buckets by dst>>12 ============
__global__ void k_bucket(const int* __restrict__ src, const int* __restrict__ dst,
                         int* __restrict__ cursor, int2* __restrict__ ebuf){
  __shared__ int hist[NBUCK];
  __shared__ int base[NBUCK];
  int t = threadIdx.x;
  hist[t] = 0;
  __syncthreads();
  int eb = blockIdx.x * 4096;
  int s[16], d[16], r[16];
#pragma unroll
  for(int k=0; k<16; k++){
    int e = eb + k*256 + t;
    s[k] = src[e];
    d[k] = dst[e];
    r[k] = atomicAdd(&hist[d[k] >> 12], 1);
  }
  __syncthreads();
  base[t] = atomicAdd(&cursor[t], hist[t]);
  __syncthreads();
#pragma unroll
  for(int k=0; k<16; k++){
    int b = d[k] >> 12;
    int pos = base[b] + r[k];
    if(pos < (b+1)*CAP)                 // capacity guard (never triggers for this data)
      ebuf[pos] = make_int2(s[k], d[k]);
  }
}

// ===== pass C: per-bucket counting sort -> rowptr/rowend/ssrc =====
__global__ void k_csr(const int2* __restrict__ ebuf, const int* __restrict__ cursor,
                      int* __restrict__ ssrc, int* __restrict__ rowptr,
                      int* __restrict__ rowend){
  __shared__ int hist[BNODES];
  __shared__ int part[256];
  int b = blockIdx.x, t = threadIdx.x;
  int cnt = cursor[b] - b*CAP;
  if(cnt > CAP) cnt = CAP;
  int ebase = b*CAP;
  for(int i=t; i<BNODES; i+=256) hist[i] = 0;
  __syncthreads();
  for(int i=t; i<cnt; i+=256){
    int2 e = ebuf[ebase + i];
    atomicAdd(&hist[e.y & (BNODES-1)], 1);
  }
  __syncthreads();
  int loc[16]; int sum = 0;
#pragma unroll
  for(int j=0; j<16; j++){ loc[j] = hist[t*16 + j]; sum += loc[j]; }
  part[t] = sum;
  __syncthreads();
#pragma unroll
  for(int off=1; off<256; off<<=1){
    int v = (t >= off) ? part[t-off] : 0;
    __syncthreads();
    part[t] += v;
    __syncthreads();
  }
  int run = part[t] - sum;   // exclusive prefix for this thread's 16 nodes
#pragma unroll
  for(int j=0; j<16; j++){
    int n = b*BNODES + t*16 + j;
    rowptr[n] = ebase + run;
    rowend[n] = ebase + run + loc[j];
    hist[t*16 + j] = run;
    run += loc[j];
  }
  __syncthreads();
  for(int i=t; i<cnt; i+=256){
    int2 e = ebuf[ebase + i];
    int pos = atomicAdd(&hist[e.y & (BNODES-1)], 1);
    ssrc[ebase + pos] = e.x;
  }
}

// ================= stats helpers =================
template<int NF>
__device__ __forceinline__ void stats_flush(float* ssum, float* ssq,
                                            float* __restrict__ stats_out){
  __shared__ float sred[2*NF];
#pragma unroll
  for(int f=0; f<NF; f++){
    float a = ssum[f], b = ssq[f];
#pragma unroll
    for(int off=1; off<64; off<<=1){
      a += __shfl_xor(a, off, 64);
      b += __shfl_xor(b, off, 64);
    }
    ssum[f] = a; ssq[f] = b;
  }
  if(threadIdx.x < 2*NF) sred[threadIdx.x] = 0.0f;
  __syncthreads();
  if((threadIdx.x & 63) == 0){
#pragma unroll
    for(int f=0; f<NF; f++){
      atomicAdd(&sred[f],      ssum[f]);
      atomicAdd(&sred[NF + f], ssq[f]);
    }
  }
  __syncthreads();
  if(threadIdx.x < 2*NF)
    atomicAdd(&stats_out[threadIdx.x * 16], sred[threadIdx.x]);  // 64B-spread counters
}

__device__ __forceinline__ void store_row16(_Float16* __restrict__ hout, int i,
                                            const float* ov){
  half8 o0, o1;
#pragma unroll
  for(int j=0; j<8; j++) o0[j] = (_Float16)ov[j];
#pragma unroll
  for(int j=0; j<4; j++) o1[j] = (_Float16)ov[8+j];
  o1[4]=(_Float16)0.f; o1[5]=(_Float16)0.f; o1[6]=(_Float16)0.f; o1[7]=(_Float16)0.f;
  half8* op = (half8*)(hout + 16*i);
  op[0] = o0; op[1] = o1;
}

// ===== conv layer 1: x[N,3] fp32 -> h[N,16] fp16, 2 nodes/thread =====
__global__ __launch_bounds__(256) void
k_layer1(const float* __restrict__ x,
         const int* __restrict__ rowptr, const int* __restrict__ rowend,
         const int* __restrict__ ssrc,
         const float* __restrict__ Wl1, const float* __restrict__ Wr1,
         const float* __restrict__ b1,
         _Float16* __restrict__ hout, float* __restrict__ stats_out){
  float ssum[12], ssq[12];
#pragma unroll
  for(int f=0; f<12; f++){ ssum[f]=0.f; ssq[f]=0.f; }
  int stride = gridDim.x*blockDim.x;
  for(int tid = blockIdx.x*blockDim.x + threadIdx.x; tid < NN/2; tid += stride){
    int i0 = 2*tid, i1 = 2*tid+1;
    int st = rowptr[i0], mid = rowptr[i1], en = rowend[i1];
    float tA0=0.f, tA1=0.f, tA2=0.f;   // total over [st,en)
    float hA0=0.f, hA1=0.f, hA2=0.f;   // over [mid,en)
    int p = st;
    for(; p+4 <= en; p += 4){
      int s0=ssrc[p], s1=ssrc[p+1], s2=ssrc[p+2], s3=ssrc[p+3];
      float m0 = (p    >= mid) ? 1.0f : 0.0f;
      float m1 = (p+1  >= mid) ? 1.0f : 0.0f;
      float m2 = (p+2  >= mid) ? 1.0f : 0.0f;
      float m3 = (p+3  >= mid) ? 1.0f : 0.0f;
      float u0=x[3*s0], u1=x[3*s0+1], u2=x[3*s0+2];
      float v0=x[3*s1], v1=x[3*s1+1], v2=x[3*s1+2];
      float w0=x[3*s2], w1=x[3*s2+1], w2=x[3*s2+2];
      float y0=x[3*s3], y1=x[3*s3+1], y2=x[3*s3+2];
      tA0 += u0+v0+w0+y0; tA1 += u1+v1+w1+y1; tA2 += u2+v2+w2+y2;
      hA0 += m0*u0 + m1*v0 + m2*w0 + m3*y0;
      hA1 += m0*u1 + m1*v1 + m2*w1 + m3*y1;
      hA2 += m0*u2 + m1*v2 + m2*w2 + m3*y2;
    }
    for(; p<en; p++){
      int s = ssrc[p];
      float m = (p >= mid) ? 1.0f : 0.0f;
      float u0=x[3*s], u1=x[3*s+1], u2=x[3*s+2];
      tA0 += u0; tA1 += u1; tA2 += u2;
      hA0 += m*u0; hA1 += m*u1; hA2 += m*u2;
    }
    int d0 = mid - st, d1 = en - mid;
    float inv0 = (d0 > 0) ? 1.0f/(float)d0 : 0.0f;
    float inv1 = (d1 > 0) ? 1.0f/(float)d1 : 0.0f;
    float a00 = (tA0-hA0)*inv0, a01 = (tA1-hA1)*inv0, a02 = (tA2-hA2)*inv0;
    float a10 = hA0*inv1,       a11 = hA1*inv1,       a12 = hA2*inv1;
    float x00 = x[3*i0], x01 = x[3*i0+1], x02 = x[3*i0+2];
    float x10 = x[3*i1], x11 = x[3*i1+1], x12 = x[3*i1+2];
    float ov0[12], ov1[12];
#pragma unroll
    for(int f=0; f<12; f++){
      float o0 = b1[f]
              + Wl1[3*f]*a00 + Wl1[3*f+1]*a01 + Wl1[3*f+2]*a02
              + Wr1[3*f]*x00 + Wr1[3*f+1]*x01 + Wr1[3*f+2]*x02;
      float o1 = b1[f]
              + Wl1[3*f]*a10 + Wl1[3*f+1]*a11 + Wl1[3*f+2]*a12
              + Wr1[3*f]*x10 + Wr1[3*f+1]*x11 + Wr1[3*f+2]*x12;
      o0 = fmaxf(o0, 0.0f); o1 = fmaxf(o1, 0.0f);
      ov0[f] = o0; ov1[f] = o1;
      ssum[f] += o0 + o1; ssq[f] += o0*o0 + o1*o1;
    }
    store_row16(hout, i0, ov0);
    store_row16(hout, i1, ov1);
  }
  stats_flush<12>(ssum, ssq, stats_out);
}

// ===== conv layers 2..8: BN folded + SAGE, fp16 -> fp16, 2 nodes/thread =====
template<bool STATS>
__global__ __launch_bounds__(256) void
k_layerk(const _Float16* __restrict__ hin,
         const int* __restrict__ rowptr, const int* __restrict__ rowend,
         const int* __restrict__ ssrc,
         const float* __restrict__ Wl, const float* __restrict__ Wr,
         const float* __restrict__ bias,
         const float* __restrict__ bng, const float* __restrict__ bnb,
         const float* __restrict__ stats_in,
         _Float16* __restrict__ hout, float* __restrict__ stats_out){
  float sc[12], sh[12];
#pragma unroll
  for(int f=0; f<12; f++){
    float m = stats_in[f*16]      * (1.0f/NN);
    float v = stats_in[(12+f)*16] * (1.0f/NN) - m*m;
    float is = rsqrtf(v + BN_EPS);
    sc[f] = bng[f]*is;
    sh[f] = bnb[f] - m*sc[f];
  }
  float ssum[12], ssq[12];
  if(STATS){
#pragma unroll
    for(int f=0; f<12; f++){ ssum[f]=0.f; ssq[f]=0.f; }
  }
  int stride = gridDim.x*blockDim.x;
  for(int tid = blockIdx.x*blockDim.x + threadIdx.x; tid < NN/2; tid += stride){
    int i0 = 2*tid, i1 = 2*tid+1;
    int st = rowptr[i0], mid = rowptr[i1], en = rowend[i1];
    float sT[12], sH[12];
#pragma unroll
    for(int k=0; k<12; k++){ sT[k]=0.f; sH[k]=0.f; }
    int p = st;
    for(; p+4 <= en; p += 4){
      int s0=ssrc[p], s1=ssrc[p+1], s2=ssrc[p+2], s3=ssrc[p+3];
      float m0 = (p   >= mid) ? 1.0f : 0.0f;
      float m1 = (p+1 >= mid) ? 1.0f : 0.0f;
      float m2 = (p+2 >= mid) ? 1.0f : 0.0f;
      float m3 = (p+3 >= mid) ? 1.0f : 0.0f;
      const half8* p0 = (const half8*)(hin + 16*s0);
      const half8* p1 = (const half8*)(hin + 16*s1);
      const half8* p2 = (const half8*)(hin + 16*s2);
      const half8* p3 = (const half8*)(hin + 16*s3);
      half8 a0=p0[0], a1=p0[1];
      half8 b0=p1[0], b1=p1[1];
      half8 c0=p2[0], c1=p2[1];
      half8 d0=p3[0], d1=p3[1];
#pragma unroll
      for(int k=0; k<8; k++){
        float fa=(float)a0[k], fb=(float)b0[k], fc=(float)c0[k], fd=(float)d0[k];
        sT[k] += (fa+fb) + (fc+fd);
        sH[k] += m0*fa + m1*fb + m2*fc + m3*fd;
      }
#pragma unroll
      for(int k=0; k<4; k++){
        float fa=(float)a1[k], fb=(float)b1[k], fc=(float)c1[k], fd=(float)d1[k];
        sT[8+k] += (fa+fb) + (fc+fd);
        sH[8+k] += m0*fa + m1*fb + m2*fc + m3*fd;
      }
    }
    for(; p<en; p++){
      int sid = ssrc[p];
      float m = (p >= mid) ? 1.0f : 0.0f;
      const half8* hp = (const half8*)(hin + 16*sid);
      half8 q0 = hp[0], q1 = hp[1];
#pragma unroll
      for(int k=0; k<8; k++){ float f=(float)q0[k]; sT[k] += f; sH[k] += m*f; }
#pragma unroll
      for(int k=0; k<4; k++){ float f=(float)q1[k]; sT[8+k] += f; sH[8+k] += m*f; }
    }
    int d0n = mid - st, d1n = en - mid;
    float inv0 = (d0n > 0) ? 1.0f/(float)d0n : 0.0f;
    float inv1 = (d1n > 0) ? 1.0f/(float)d1n : 0.0f;
    float zm0  = (d0n > 0) ? 1.0f : 0.0f;
    float zm1  = (d1n > 0) ? 1.0f : 0.0f;
    const half8* hp0 = (const half8*)(hin + 16*i0);
    const half8* hp1 = (const half8*)(hin + 16*i1);
    half8 r00 = hp0[0], r01 = hp0[1];
    half8 r10 = hp1[0], r11 = hp1[1];
    float agg0[12], agg1[12], hn0[12], hn1[12];
#pragma unroll
    for(int k=0; k<12; k++){
      float hv0 = (k<8) ? (float)r00[k] : (float)r01[k-8];
      float hv1 = (k<8) ? (float)r10[k] : (float)r11[k-8];
      agg0[k] = ((sT[k]-sH[k])*inv0*sc[k] + sh[k]) * zm0;  // BN-of-mean; deg=0 -> 0
      agg1[k] = (sH[k]*inv1*sc[k] + sh[k]) * zm1;
      hn0[k]  = hv0*sc[k] + sh[k];
      hn1[k]  = hv1*sc[k] + sh[k];
    }
    float ov0[12], ov1[12];
#pragma unroll
    for(int f=0; f<12; f++){
      float o0 = bias[f], o1 = bias[f];
#pragma unroll
      for(int k=0; k<12; k++){ o0 += Wl[12*f+k]*agg0[k]; o1 += Wl[12*f+k]*agg1[k]; }
#pragma unroll
      for(int k=0; k<12; k++){ o0 += Wr[12*f+k]*hn0[k];  o1 += Wr[12*f+k]*hn1[k]; }
      o0 = fmaxf(o0, 0.0f); o1 = fmaxf(o1, 0.0f);
      ov0[f] = o0; ov1[f] = o1;
      if(STATS){ ssum[f] += o0 + o1; ssq[f] += o0*o0 + o1*o1; }
    }
    store_row16(hout, i0, ov0);
    store_row16(hout, i1, ov1);
  }
  if(STATS) stats_flush<12>(ssum, ssq, stats_out);
}

// ========== head linear on [2N,6] stored as padded fp16 [N,16] ==========
// one thread = one padded row = two consecutive [2N,6] sub-rows
template<bool FIRST>
__global__ void k_head(const _Float16* __restrict__ zin,
                       const float* __restrict__ W, const float* __restrict__ bv,
                       const float* __restrict__ g6, const float* __restrict__ b6,
                       const float* __restrict__ stats_in,
                       _Float16* __restrict__ zout, float* __restrict__ stats_out){
  float sc[6], sh[6];
  if(!FIRST){
#pragma unroll
    for(int k=0; k<6; k++){
      float m = stats_in[k*16]     * (1.0f/(2.0f*NN));
      float v = stats_in[(6+k)*16] * (1.0f/(2.0f*NN)) - m*m;
      float is = rsqrtf(v + BN_EPS);
      sc[k] = g6[k]*is;
      sh[k] = b6[k] - m*sc[k];
    }
  }
  float ssum[6], ssq[6];
#pragma unroll
  for(int f=0; f<6; f++){ ssum[f]=0.f; ssq[f]=0.f; }
  int stride = gridDim.x*blockDim.x;
  for(int i = blockIdx.x*blockDim.x + threadIdx.x; i < NN; i += stride){
    const half8* zp = (const half8*)(zin + 16*i);
    half8 a = zp[0], b = zp[1];
    float t0[6] = {(float)a[0],(float)a[1],(float)a[2],(float)a[3],(float)a[4],(float)a[5]};
    float t1[6] = {(float)a[6],(float)a[7],(float)b[0],(float)b[1],(float)b[2],(float)b[3]};
    if(!FIRST){
#pragma unroll
      for(int k=0; k<6; k++){
        t0[k] = fmaxf(t0[k]*sc[k] + sh[k], 0.0f);
        t1[k] = fmaxf(t1[k]*sc[k] + sh[k], 0.0f);
      }
    }
    float ov[12];
#pragma unroll
    for(int f=0; f<6; f++){
      float o0 = bv[f], o1 = bv[f];
#pragma unroll
      for(int k=0; k<6; k++){ o0 += W[6*f+k]*t0[k]; o1 += W[6*f+k]*t1[k]; }
      ov[f] = o0; ov[6+f] = o1;
      ssum[f] += o0 + o1; ssq[f] += o0*o0 + o1*o1;
    }
    store_row16(zout, i, ov);
  }
  stats_flush<6>(ssum, ssq, stats_out);
}

// ========== final: BN+ReLU + Linear(6,1) + sigmoid; one thread = 2 outputs ==========
__global__ void k_out(const _Float16* __restrict__ zin,
                      const float* __restrict__ g6, const float* __restrict__ b6,
                      const float* __restrict__ stats_in,
                      const float* __restrict__ outW, const float* __restrict__ outb,
                      float* __restrict__ out){
  float sc[6], sh[6], w[6];
#pragma unroll
  for(int k=0; k<6; k++){
    float m = stats_in[k*16]     * (1.0f/(2.0f*NN));
    float v = stats_in[(6+k)*16] * (1.0f/(2.0f*NN)) - m*m;
    float is = rsqrtf(v + BN_EPS);
    sc[k] = g6[k]*is;
    sh[k] = b6[k] - m*sc[k];
    w[k] = outW[k];
  }
  float ob = outb[0];
  int stride = gridDim.x*blockDim.x;
  for(int i = blockIdx.x*blockDim.x + threadIdx.x; i < NN; i += stride){
    const half8* zp = (const half8*)(zin + 16*i);
    half8 a = zp[0], b = zp[1];
    float t0[6] = {(float)a[0],(float)a[1],(float)a[2],(float)a[3],(float)a[4],(float)a[5]};
    float t1[6] = {(float)a[6],(float)a[7],(float)b[0],(float)b[1],(float)b[2],(float)b[3]};
    float o0 = ob, o1 = ob;
#pragma unroll
    for(int k=0; k<6; k++){
      o0 += w[k] * fmaxf(t0[k]*sc[k] + sh[k], 0.0f);
      o1 += w[k] * fmaxf(t1[k]*sc[k] + sh[k], 0.0f);
    }
    float2 r;
    r.x = 1.0f / (1.0f + expf(-o0));
    r.y = 1.0f / (1.0f + expf(-o1));
    ((float2*)out)[i] = r;
  }
}

extern "C" void kernel_launch(void* const* d_in, const int* in_sizes, int n_in,
                              void* d_out, int out_size, void* d_ws, size_t ws_size,
                              hipStream_t stream){
  const float* x    = (const float*)d_in[0];
  const int*   ei   = (const int*)  d_in[1];
  const float* Wl1  = (const float*)d_in[2];
  const float* Wr1  = (const float*)d_in[3];
  const float* b1   = (const float*)d_in[4];
  const float* Wl   = (const float*)d_in[5];
  const float* Wr   = (const float*)d_in[6];
  const float* bb   = (const float*)d_in[7];
  const float* bng  = (const float*)d_in[8];
  const float* bnb  = (const float*)d_in[9];
  const float* linW = (const float*)d_in[10];
  const float* linb = (const float*)d_in[11];
  const float* bn6g = (const float*)d_in[12];
  const float* bn6b = (const float*)d_in[13];
  const float* outW = (const float*)d_in[14];
  const float* outb = (const float*)d_in[15];
  float* out = (float*)d_out;

  char* ws = (char*)d_ws;
  int*      ssrc   = (int*)     (ws + OFF_SSRC);
  int*      rowptr = (int*)     (ws + OFF_ROWPTR);
  int*      rowend = (int*)     (ws + OFF_ROWEND);
  int*      cursor = (int*)     (ws + OFF_CURSOR);
  float*    stats  = (float*)   (ws + OFF_STATS);
  _Float16* hA     = (_Float16*)(ws + OFF_HA);
  _Float16* hB     = (_Float16*)(ws + OFF_HB);
  int2*     ebuf   = (int2*)    (ws + OFF_EBUF);   // aliases hA/hB; dead after k_csr

  const int* srcp = ei;
  const int* dstp = ei + EE;

  k_init  <<<1,    256, 0, stream>>>(cursor, stats);
  k_bucket<<<1024, 256, 0, stream>>>(srcp, dstp, cursor, ebuf);
  k_csr   <<<NBUCK,256, 0, stream>>>(ebuf, cursor, ssrc, rowptr, rowend);

  // conv1 (stats -> slot 0)
  k_layer1<<<GBLK, 256, 0, stream>>>(x, rowptr, rowend, ssrc, Wl1, Wr1, b1, hA, stats);

  // conv2..conv8
  _Float16* hi = hA; _Float16* ho = hB;
  for(int l=0; l<7; l++){
    const float* st_in = stats + l*SS;
    float* st_out      = stats + (l+1)*SS;
    if(l < 6)
      k_layerk<true><<<GBLK, 256, 0, stream>>>(hi, rowptr, rowend, ssrc,
        Wl + 144*l, Wr + 144*l, bb + 12*l, bng + 12*l, bnb + 12*l, st_in, ho, st_out);
    else
      k_layerk<false><<<GBLK, 256, 0, stream>>>(hi, rowptr, rowend, ssrc,
        Wl + 144*l, Wr + 144*l, bb + 12*l, bng + 12*l, bnb + 12*l, st_in, ho, st_out);
    _Float16* t = hi; hi = ho; ho = t;
  }
  // hi = conv8 output, padded fp16 rows; head views each row as two [2N,6] sub-rows

  // head: z1 (stats slot 7)
  k_head<true> <<<2048, 256, 0, stream>>>(hi, linW, linb, bn6g, bn6b,
                                          stats + 7*SS, ho, stats + 7*SS);
  { _Float16* t = hi; hi = ho; ho = t; }
  // z2 (slot 8)
  k_head<false><<<2048, 256, 0, stream>>>(hi, linW, linb, bn6g, bn6b,
                                          stats + 7*SS, ho, stats + 8*SS);
  { _Float16* t = hi; hi = ho; ho = t; }
  // z3 (slot 9)
  k_head<false><<<2048, 256, 0, stream>>>(hi, linW, linb, bn6g, bn6b,
                                          stats + 8*SS, ho, stats + 9*SS);
  { _Float16* t = hi; hi = ho; ho = t; }
  // final
  k_out<<<2048, 256, 0, stream>>>(hi, bn6g, bn6b, stats + 9*SS, outW, outb, out);
}